// Round 6
// baseline (1583.841 us; speedup 1.0000x reference)
//
#include <hip/hip_runtime.h>
#include <cstdint>
#include <cstddef>

// ---------------------------------------------------------------------------
// NeuralODE persistent kernel, round 6: measured-XCD grouping + fence-free
// barriers.
//   z' = f(z,t) = tanh([z,t]@W1 + b1) @ W2 + b2, Euler, 20 steps.
//   bs=1024, d=1024, hidden=2048. fp32 in/out; bf16 MFMA inside.
//
// R5 lesson: groups formed by bid%32 spanned XCDs -> every barrier took the
// agent-fence path -> ~20K L2 writeback/invalidates -> FETCH 2 GB, MfmaUtil
// 5%. Fix: blocks self-organize into groups of 16 on their OWN XCD (runtime
// s_getreg(XCC_ID) + rank + prefix sum over a one-time device barrier). LDS
// padded to 56 KB so exactly 2 blocks/CU fit -> 64 blocks/XCD -> all groups
// single-XCD. Steady-state barrier: relaxed add + relaxed spin on XCD-local
// L2 line, NO fences; cross-block data (zbf/Hbf) is read with SC0 (L1-bypass)
// global_load_lds so the XCD-shared L2 provides coherence; weights stay
// L1/L2-cached. Weight tile-0 prefetch overlaps the barrier spin.
// ---------------------------------------------------------------------------

typedef __bf16 bf16x8 __attribute__((ext_vector_type(8)));
typedef float f32x4 __attribute__((ext_vector_type(4)));

__device__ __forceinline__ unsigned short f2bf(float f) {
  union { float f; unsigned u; } v; v.f = f;
  unsigned r = v.u + 0x7fffu + ((v.u >> 16) & 1u);   // RNE
  return (unsigned short)(r >> 16);
}

// fast tanh: 1 - 2/(1+2^(2*log2e*x)); exact at +/-inf
__device__ __forceinline__ float fast_tanh(float x) {
  float e = __builtin_amdgcn_exp2f(x * 2.8853900817779268f);
  return 1.0f - 2.0f * __builtin_amdgcn_rcpf(1.0f + e);
}

// ---------------- prep: tiled transpose fp32 -> bf16 (out[cols][rows]) ------
__global__ void transpose_to_bf16(const float* __restrict__ in,
                                  unsigned short* __restrict__ out,
                                  int rows, int cols) {
  __shared__ float tile[32][33];
  int c0 = blockIdx.x * 32, r0 = blockIdx.y * 32;
  int tx = threadIdx.x, ty = threadIdx.y;
#pragma unroll
  for (int j = 0; j < 32; j += 8)
    tile[ty + j][tx] = in[(size_t)(r0 + ty + j) * cols + (c0 + tx)];
  __syncthreads();
#pragma unroll
  for (int j = 0; j < 32; j += 8)
    out[(size_t)(c0 + ty + j) * rows + (r0 + tx)] = f2bf(tile[tx][ty + j]);
}

// ---------------- prep: z copies + last W1 row + barrier zero ---------------
__global__ void prep_misc(const float* __restrict__ z0,
                          float* __restrict__ zf,
                          unsigned short* __restrict__ zbf,
                          const float* __restrict__ W1,
                          float* __restrict__ w1l,
                          unsigned* __restrict__ bars, int n, int nl) {
  int i = blockIdx.x * blockDim.x + threadIdx.x;
  if (i < n) { float v = z0[i]; zf[i] = v; zbf[i] = f2bf(v); }
  if (i < nl) { w1l[i] = W1[(size_t)1024 * 2048 + i]; bars[i] = 0u; }
}

// stage 32 rows x 64 bf16 via global_load_lds, XOR-swizzled 16B chunks:
// row r slot s holds logical chunk s^(r&7)  -> conflict-free ds_read_b128.
// AUX bit0 = SC0: L1-bypass (XCD-L2-coherent) — use for cross-block data.
template <int AUX>
__device__ __forceinline__ void stage32(const unsigned short* __restrict__ g,
                                        size_t ld, int row0, int k0,
                                        unsigned short* lds, int tid) {
  int r = tid >> 3;
  int c = (tid & 7) ^ (r & 7);
  __builtin_amdgcn_global_load_lds(
      (const __attribute__((address_space(1))) void*)(
          g + (size_t)(row0 + r) * ld + k0 + c * 8),
      (__attribute__((address_space(3))) void*)(lds + tid * 8), 16, 0, AUX);
}

__device__ __forceinline__ bf16x8 frag_ld(const unsigned short* lds, int row,
                                          int chunk_logical, int x) {
  return *(const bf16x8*)(lds + row * 64 + ((chunk_logical ^ x) << 3));
}

// group barrier arrive+wait (entry __syncthreads done by caller, so block's
// stores are drained to L2 before the add issues). fast: single-XCD group,
// relaxed add + relaxed spin, no cache ops (SC0 loads handle data coherence).
// heavy: cross-XCD fallback with release/acquire.
__device__ __forceinline__ void arrive_wait(unsigned* bar, unsigned target,
                                            bool fast) {
  if (threadIdx.x == 0) {
    if (fast) {
      __hip_atomic_fetch_add(bar, 1u, __ATOMIC_RELAXED,
                             __HIP_MEMORY_SCOPE_AGENT);
      while (__hip_atomic_load(bar, __ATOMIC_RELAXED,
                               __HIP_MEMORY_SCOPE_AGENT) < target)
        __builtin_amdgcn_s_sleep(1);
    } else {
      __hip_atomic_fetch_add(bar, 1u, __ATOMIC_RELEASE,
                             __HIP_MEMORY_SCOPE_AGENT);
      while (__hip_atomic_load(bar, __ATOMIC_RELAXED,
                               __HIP_MEMORY_SCOPE_AGENT) < target)
        __builtin_amdgcn_s_sleep(1);
      __builtin_amdgcn_fence(__ATOMIC_ACQUIRE, "agent");
    }
  }
  __syncthreads();
}

// ---------------- the persistent ODE kernel ---------------------------------
// bars layout (u32): [0..7] per-XCD rank counters; [8],[9] device barriers;
// [16+g*16] group phase counter; [17+g*16] group XCC mask.
__global__ __launch_bounds__(256, 2) void ode_persistent(
    const unsigned short* __restrict__ W1T,   // [2048][1024] bf16 N-major
    const unsigned short* __restrict__ W2T,   // [1024][2048] bf16 N-major
    const float* __restrict__ b1v, const float* __restrict__ w1l,
    const float* __restrict__ b2v,
    unsigned short* __restrict__ zbf,         // [1024][1024] bf16
    float* __restrict__ zf,                   // [1024][1024] f32
    unsigned short* __restrict__ Hbf,         // [1024][2048] bf16
    float* __restrict__ out,                  // d_out
    unsigned* __restrict__ bars) {
  // 56 KB LDS (use 48): forces max 2 blocks/CU -> exactly 64 blocks/XCD.
  __shared__ __align__(16) unsigned short lds[28672];
  __shared__ unsigned sh_slot;
  const int tid = threadIdx.x;
  const int lane = tid & 63, wid = tid >> 6;
  const int l15 = lane & 15, q = lane >> 4, x = l15 & 7;
  const float h = 0.05f;

  // ---- one-time: self-organize into XCD-local groups of 16 ----
  unsigned xcc;
  asm volatile("s_getreg_b32 %0, hwreg(HW_REG_XCC_ID)" : "=s"(xcc));
  xcc &= 15u;
  if (tid == 0) {
    unsigned rank = __hip_atomic_fetch_add(&bars[xcc], 1u, __ATOMIC_RELAXED,
                                           __HIP_MEMORY_SCOPE_AGENT);
    __hip_atomic_fetch_add(&bars[8], 1u, __ATOMIC_RELEASE,
                           __HIP_MEMORY_SCOPE_AGENT);
    while (__hip_atomic_load(&bars[8], __ATOMIC_RELAXED,
                             __HIP_MEMORY_SCOPE_AGENT) < 512u)
      __builtin_amdgcn_s_sleep(8);
    __builtin_amdgcn_fence(__ATOMIC_ACQUIRE, "agent");
    unsigned base = 0;
    for (unsigned i = 0; i < xcc; ++i)
      base += __hip_atomic_load(&bars[i], __ATOMIC_RELAXED,
                                __HIP_MEMORY_SCOPE_AGENT);
    unsigned slot = base + rank;
    __hip_atomic_fetch_or(&bars[17 + (slot >> 4) * 16], 1u << xcc,
                          __ATOMIC_RELAXED, __HIP_MEMORY_SCOPE_AGENT);
    __hip_atomic_fetch_add(&bars[9], 1u, __ATOMIC_RELEASE,
                           __HIP_MEMORY_SCOPE_AGENT);
    while (__hip_atomic_load(&bars[9], __ATOMIC_RELAXED,
                             __HIP_MEMORY_SCOPE_AGENT) < 512u)
      __builtin_amdgcn_s_sleep(8);
    __builtin_amdgcn_fence(__ATOMIC_ACQUIRE, "agent");
    unsigned msk = __hip_atomic_load(&bars[17 + (slot >> 4) * 16],
                                     __ATOMIC_RELAXED,
                                     __HIP_MEMORY_SCOPE_AGENT);
    sh_slot = slot | (((msk & (msk - 1u)) == 0u) ? 0x80000000u : 0u);
  }
  __syncthreads();
  const unsigned slotw = sh_slot;
  const bool fast = (slotw >> 31) != 0u;
  const int slot = (int)(slotw & 0xFFFFu);
  const int g = slot >> 4, mem = slot & 15;
  unsigned* bar = bars + 16 + g * 16;
  const int row0 = g * 32;       // stripe rows [row0, row0+32)
  const int n1 = mem * 128;      // gemm1 H-col base
  const int n2 = mem * 64;       // gemm2 z-col base
  unsigned ph = 0;
  float tval = 0.0f;

  unsigned short* Ab1 = lds;          // gemm1 A: [2][2048]
  unsigned short* Bb1 = lds + 4096;   // gemm1 B: [2][8192]
  // pre-stage gemm1 B tile0 for step 0
#pragma unroll
  for (int i = 0; i < 4; ++i)
    stage32<0>(W1T, 1024, n1 + 32 * i, 0, Bb1 + i * 2048, tid);

  for (int step = 0; step < 20; ++step) {
    if (step % 5 == 0) tval = 0.25f * (float)(step / 5);

    // ---------------- gemm1: H[stripe, n1:n1+128] -------------------------
    {
      f32x4 acc[2][2] = {};
      const int wn = wid * 32;  // 4 waves cover 128 cols
      stage32<1>(zbf, 1024, row0, 0, Ab1, tid);   // A tile0 (SC0: cross-block)
      __syncthreads();
      int cur = 0;
      for (int k0 = 0; k0 < 1024; k0 += 64) {
        int kn = k0 + 64;
        if (kn < 1024) {
          stage32<1>(zbf, 1024, row0, kn, Ab1 + (cur ^ 1) * 2048, tid);
#pragma unroll
          for (int i = 0; i < 4; ++i)
            stage32<0>(W1T, 1024, n1 + 32 * i, kn,
                       Bb1 + (cur ^ 1) * 8192 + i * 2048, tid);
        }
        const unsigned short* A = Ab1 + cur * 2048;
        const unsigned short* B = Bb1 + cur * 8192;
#pragma unroll
        for (int kk = 0; kk < 2; ++kk) {
          bf16x8 a[2], b[2];
#pragma unroll
          for (int im = 0; im < 2; ++im)
            a[im] = frag_ld(A, im * 16 + l15, (kk << 2) + q, x);
#pragma unroll
          for (int jn = 0; jn < 2; ++jn)
            b[jn] = frag_ld(B, wn + jn * 16 + l15, (kk << 2) + q, x);
#pragma unroll
          for (int im = 0; im < 2; ++im)
#pragma unroll
            for (int jn = 0; jn < 2; ++jn)
              acc[im][jn] = __builtin_amdgcn_mfma_f32_16x16x32_bf16(
                  a[im], b[jn], acc[im][jn], 0, 0, 0);
        }
        __syncthreads();
        cur ^= 1;
      }
#pragma unroll
      for (int jn = 0; jn < 2; ++jn) {
        int col = n1 + wn + jn * 16 + l15;
        float bb = b1v[col] + tval * w1l[col];
#pragma unroll
        for (int im = 0; im < 2; ++im) {
          int rowb = row0 + im * 16 + q * 4;
#pragma unroll
          for (int r = 0; r < 4; ++r)
            Hbf[(size_t)(rowb + r) * 2048 + col] =
                f2bf(fast_tanh(acc[im][jn][r] + bb));
        }
      }
    }
    // barrier: entry sync drains H stores; prefetch gemm2 B tile0 during spin
    __syncthreads();
    stage32<0>(W2T, 2048, n2, 0, lds + 8192, tid);
    stage32<0>(W2T, 2048, n2 + 32, 0, lds + 8192 + 2048, tid);
    stage32<0>(W2T, 2048, n2, 1024, lds + 8192 + 4096, tid);
    stage32<0>(W2T, 2048, n2 + 32, 1024, lds + 8192 + 4096 + 2048, tid);
    arrive_wait(bar, 16u * (++ph), fast);

    // ---------------- gemm2: z'[stripe, n2:n2+64] -------------------------
    // LDS: A2[c][hf] = lds + (c*2+hf)*2048 ; B2[c][hf] = lds+8192+(c*2+hf)*4096
    {
      f32x4 acc[2][2] = {};
      const int half = wid >> 1, wsx = wid & 1;
      const int wn = wsx * 32;
      stage32<1>(Hbf, 2048, row0, 0, lds, tid);            // A2[0][0] (SC0)
      stage32<1>(Hbf, 2048, row0, 1024, lds + 2048, tid);  // A2[0][1]
      __syncthreads();
      int cur = 0;
      for (int k0 = 0; k0 < 1024; k0 += 64) {
        int kn = k0 + 64;
        if (kn < 1024) {
          int c2 = (cur ^ 1) * 2;
          stage32<1>(Hbf, 2048, row0, kn, lds + (c2 + 0) * 2048, tid);
          stage32<1>(Hbf, 2048, row0, kn + 1024, lds + (c2 + 1) * 2048, tid);
          stage32<0>(W2T, 2048, n2, kn, lds + 8192 + (c2 + 0) * 4096, tid);
          stage32<0>(W2T, 2048, n2 + 32, kn,
                     lds + 8192 + (c2 + 0) * 4096 + 2048, tid);
          stage32<0>(W2T, 2048, n2, kn + 1024,
                     lds + 8192 + (c2 + 1) * 4096, tid);
          stage32<0>(W2T, 2048, n2 + 32, kn + 1024,
                     lds + 8192 + (c2 + 1) * 4096 + 2048, tid);
        }
        const unsigned short* A = lds + (cur * 2 + half) * 2048;
        const unsigned short* B = lds + 8192 + (cur * 2 + half) * 4096;
#pragma unroll
        for (int kk = 0; kk < 2; ++kk) {
          bf16x8 a[2], b[2];
#pragma unroll
          for (int im = 0; im < 2; ++im)
            a[im] = frag_ld(A, im * 16 + l15, (kk << 2) + q, x);
#pragma unroll
          for (int jn = 0; jn < 2; ++jn)
            b[jn] = frag_ld(B, wn + jn * 16 + l15, (kk << 2) + q, x);
#pragma unroll
          for (int im = 0; im < 2; ++im)
#pragma unroll
            for (int jn = 0; jn < 2; ++jn)
              acc[im][jn] = __builtin_amdgcn_mfma_f32_16x16x32_bf16(
                  a[im], b[jn], acc[im][jn], 0, 0, 0);
        }
        __syncthreads();
        cur ^= 1;
      }
      // split-K reduce (lds as f32, stride 65)
      float* red = (float*)lds;
      if (half == 1) {
#pragma unroll
        for (int im = 0; im < 2; ++im)
#pragma unroll
          for (int jn = 0; jn < 2; ++jn) {
            int col = wn + jn * 16 + l15;
#pragma unroll
            for (int r = 0; r < 4; ++r)
              red[(im * 16 + q * 4 + r) * 65 + col] = acc[im][jn][r];
          }
      }
      __syncthreads();
      if (half == 0) {
#pragma unroll
        for (int jn = 0; jn < 2; ++jn) {
          int coll = wn + jn * 16 + l15;
          int col = n2 + coll;
          float bb = b2v[col];
#pragma unroll
          for (int im = 0; im < 2; ++im) {
            int rowl = im * 16 + q * 4;
#pragma unroll
            for (int r = 0; r < 4; ++r) {
              float s = acc[im][jn][r] + red[(rowl + r) * 65 + coll];
              size_t gidx = (size_t)(row0 + rowl + r) * 1024 + col;
              float zv = zf[gidx] + h * (s + bb);
              zf[gidx] = zv;
              zbf[gidx] = f2bf(zv);
              if (step == 19) out[gidx] = zv;
            }
          }
        }
      }
    }
    if (step < 19) {
      // barrier: entry sync drains z stores; prefetch next gemm1 B tile0
      __syncthreads();
#pragma unroll
      for (int i = 0; i < 4; ++i)
        stage32<0>(W1T, 1024, n1 + 32 * i, 0, Bb1 + i * 2048, tid);
      arrive_wait(bar, 16u * (++ph), fast);
    }
    tval += h;
  }
}

// ---------------------------------------------------------------------------
extern "C" void kernel_launch(void* const* d_in, const int* in_sizes, int n_in,
                              void* d_out, int out_size, void* d_ws,
                              size_t ws_size, hipStream_t stream) {
  const float* z0 = (const float*)d_in[0];
  // d_in[1] = t (linspace 0..1, 5) — reproduced exactly in f32 arithmetic
  const float* W1 = (const float*)d_in[2];
  const float* b1 = (const float*)d_in[3];
  const float* W2 = (const float*)d_in[4];
  const float* b2 = (const float*)d_in[5];
  float* out = (float*)d_out;

  char* ws = (char*)d_ws;
  unsigned short* W1T = (unsigned short*)(ws + 0);              // 4 MB
  unsigned short* W2T = (unsigned short*)(ws + (4u << 20));     // 4 MB
  unsigned short* zbf = (unsigned short*)(ws + (8u << 20));     // 2 MB
  unsigned short* Hbf = (unsigned short*)(ws + (10u << 20));    // 4 MB
  float* zf = (float*)(ws + (14u << 20));                       // 4 MB
  float* w1l = (float*)(ws + (18u << 20));                      // 8 KB
  unsigned* bars = (unsigned*)(ws + (19u << 20));               // 8 KB

  transpose_to_bf16<<<dim3(64, 32), dim3(32, 8), 0, stream>>>(W1, W1T, 1024, 2048);
  transpose_to_bf16<<<dim3(32, 64), dim3(32, 8), 0, stream>>>(W2, W2T, 2048, 1024);
  prep_misc<<<4096, 256, 0, stream>>>(z0, zf, zbf, W1, w1l, bars,
                                      1024 * 1024, 2048);

  ode_persistent<<<512, 256, 0, stream>>>(W1T, W2T, b1, w1l, b2, zbf, zf, Hbf,
                                          out, bars);
}

// Round 7
// 485.331 us; speedup vs baseline: 3.2634x; 3.2634x over previous
//
#include <hip/hip_runtime.h>
#include <cstdint>
#include <cstddef>

// ---------------------------------------------------------------------------
// NeuralODE, multi-kernel (R2 structure) + software-pipelined K-loops.
//   z' = f(z,t) = tanh([z,t]@W1 + b1) @ W2 + b2, Euler, 20 steps.
//   bs=1024, d=1024, hidden=2048. fp32 in/out; bf16 MFMA inside.
//
// Per step: gemm1 (H=tanh(...), 512 blocks 64x64) ; gemm2 (z'=z+h*f, 512
// blocks 32x64). K-loop: raw `s_waitcnt vmcnt(N) lgkmcnt(0)` + `s_barrier`
// with 3/4-buffered LDS -> 2 tiles in flight at all times (the __syncthreads
// vmcnt(0) drain was the MLP killer: ~1.5 TB/s effective fabric; m13 shows
// 6.3 achievable). 2D XCD-patch swizzle keeps each XCD's per-launch working
// set (~2-3 MB) inside its 4 MB L2.
// ---------------------------------------------------------------------------

typedef __bf16 bf16x8 __attribute__((ext_vector_type(8)));
typedef float f32x4 __attribute__((ext_vector_type(4)));

#define WAITV(N) asm volatile("s_waitcnt vmcnt(" #N ") lgkmcnt(0)" ::: "memory")
#define BARRIER() asm volatile("s_barrier" ::: "memory")

__device__ __forceinline__ unsigned short f2bf(float f) {
  union { float f; unsigned u; } v; v.f = f;
  unsigned r = v.u + 0x7fffu + ((v.u >> 16) & 1u);   // RNE
  return (unsigned short)(r >> 16);
}

// fast tanh: 1 - 2/(1+2^(2*log2e*x)); exact at +/-inf
__device__ __forceinline__ float fast_tanh(float x) {
  float e = __builtin_amdgcn_exp2f(x * 2.8853900817779268f);
  return 1.0f - 2.0f * __builtin_amdgcn_rcpf(1.0f + e);
}

// ---------------- prep: tiled transpose fp32 -> bf16 (out[cols][rows]) ------
__global__ void transpose_to_bf16(const float* __restrict__ in,
                                  unsigned short* __restrict__ out,
                                  int rows, int cols) {
  __shared__ float tile[32][33];
  int c0 = blockIdx.x * 32, r0 = blockIdx.y * 32;
  int tx = threadIdx.x, ty = threadIdx.y;
#pragma unroll
  for (int j = 0; j < 32; j += 8)
    tile[ty + j][tx] = in[(size_t)(r0 + ty + j) * cols + (c0 + tx)];
  __syncthreads();
#pragma unroll
  for (int j = 0; j < 32; j += 8)
    out[(size_t)(c0 + ty + j) * rows + (r0 + tx)] = f2bf(tile[tx][ty + j]);
}

// ---------------- prep: z copies + last W1 row ------------------------------
__global__ void prep_misc(const float* __restrict__ z0,
                          float* __restrict__ zf,
                          unsigned short* __restrict__ zbf,
                          const float* __restrict__ W1,
                          float* __restrict__ w1l, int n, int nl) {
  int i = blockIdx.x * blockDim.x + threadIdx.x;
  if (i < n) { float v = z0[i]; zf[i] = v; zbf[i] = f2bf(v); }
  if (i < nl) { w1l[i] = W1[(size_t)1024 * 2048 + i]; }
}

// stage 32 rows x 64 bf16 via global_load_lds, XOR-swizzled 16B chunks:
// row r slot s holds logical chunk s^(r&7)  -> conflict-free ds_read_b128.
__device__ __forceinline__ void stage32(const unsigned short* __restrict__ g,
                                        size_t ld, int row0, int k0,
                                        unsigned short* lds, int tid) {
  int r = tid >> 3;
  int c = (tid & 7) ^ (r & 7);
  __builtin_amdgcn_global_load_lds(
      (const __attribute__((address_space(1))) void*)(
          g + (size_t)(row0 + r) * ld + k0 + c * 8),
      (__attribute__((address_space(3))) void*)(lds + tid * 8), 16, 0, 0);
}

__device__ __forceinline__ bf16x8 frag_ld(const unsigned short* lds, int row,
                                          int chunk_logical, int x) {
  return *(const bf16x8*)(lds + row * 64 + ((chunk_logical ^ x) << 3));
}

// ---------------- GEMM1: H = tanh(Zb @ W1T^T + b1 + t*w1l) ------------------
// 64x64 tiles, K=1024 (16 BK=64 tiles), 3-buffer pipeline, 2x2 waves of 32x32.
// 2D XCD swizzle: XCD x -> m-tiles 8*(x&1).., n-tiles 8*(x>>1)..
__global__ __launch_bounds__(256, 2) void gemm1_kernel(
    const unsigned short* __restrict__ Zb,    // [1024][1024] bf16
    const unsigned short* __restrict__ W1T,   // [2048][1024] bf16 (N-major)
    unsigned short* __restrict__ H,           // [1024][2048] bf16
    const float* __restrict__ b1, const float* __restrict__ w1l, float tval) {
  __shared__ __align__(16) unsigned short lds[24576];  // 48 KB
  unsigned short* GA = lds;            // 3 bufs x 4096 (2 chunks of 32 rows)
  unsigned short* GB = lds + 12288;    // 3 bufs x 4096
  const int tid = threadIdx.x;
  const int lane = tid & 63, wid = tid >> 6;
  const int l15 = lane & 15, q = lane >> 4, x = l15 & 7;
  const int wm = (wid & 1) * 32, wn = (wid >> 1) * 32;
  const int bid = blockIdx.x;
  const int xcd = bid & 7, loc = bid >> 3;
  const int mt = (loc & 7) | ((xcd & 1) << 3);    // 0..15
  const int nt = (loc >> 3) | ((xcd >> 1) << 3);  // 0..31
  const int m0 = mt * 64, n0 = nt * 64;

  f32x4 acc[2][2] = {};

  // stage tile t into buf b  (L = 4 loads/thread)
  auto stage_tile = [&](int t, int b) {
    int k = t * 64;
    stage32(Zb, 1024, m0, k, GA + b * 4096, tid);
    stage32(Zb, 1024, m0 + 32, k, GA + b * 4096 + 2048, tid);
    stage32(W1T, 1024, n0, k, GB + b * 4096, tid);
    stage32(W1T, 1024, n0 + 32, k, GB + b * 4096 + 2048, tid);
  };
  auto compute = [&](int b) {
    const unsigned short* A = GA + b * 4096 + (wid & 1) * 2048;
    const unsigned short* B = GB + b * 4096 + (wid >> 1) * 2048;
#pragma unroll
    for (int kk = 0; kk < 2; ++kk) {
      bf16x8 a[2], bb[2];
#pragma unroll
      for (int im = 0; im < 2; ++im)
        a[im] = frag_ld(A, im * 16 + l15, (kk << 2) + q, x);
#pragma unroll
      for (int jn = 0; jn < 2; ++jn)
        bb[jn] = frag_ld(B, jn * 16 + l15, (kk << 2) + q, x);
#pragma unroll
      for (int im = 0; im < 2; ++im)
#pragma unroll
        for (int jn = 0; jn < 2; ++jn)
          acc[im][jn] = __builtin_amdgcn_mfma_f32_16x16x32_bf16(
              a[im], bb[jn], acc[im][jn], 0, 0, 0);
    }
  };

  stage_tile(0, 0);
  stage_tile(1, 1);
  for (int i = 0; i < 15; ++i) {
    WAITV(4);    // tile i arrived; tile i+1 (4 loads) still in flight
    BARRIER();
    if (i < 14) stage_tile(i + 2, (i + 2) % 3);
    compute(i % 3);
  }
  WAITV(0);
  BARRIER();
  compute(15 % 3);

#pragma unroll
  for (int jn = 0; jn < 2; ++jn) {
    int col = n0 + wn + jn * 16 + l15;
    float bb = b1[col] + tval * w1l[col];
#pragma unroll
    for (int im = 0; im < 2; ++im) {
      int rowb = m0 + wm + im * 16 + q * 4;
#pragma unroll
      for (int r = 0; r < 4; ++r)
        H[(size_t)(rowb + r) * 2048 + col] =
            f2bf(fast_tanh(acc[im][jn][r] + bb));
    }
  }
}

// ---------------- GEMM2: z' = zf + h*(H @ W2T^T + b2) -----------------------
// 32x64 tiles, K=2048 (32 BK=64 tiles), 4-buffer pipeline, 1x4 waves of 32x16.
// 2D XCD swizzle: XCD x -> m-tiles 8*(x&3).., n-tiles 8*(x>>2)..
__global__ __launch_bounds__(256, 2) void gemm2_kernel(
    const unsigned short* __restrict__ Hb,    // [1024][2048] bf16
    const unsigned short* __restrict__ W2T,   // [1024][2048] bf16 (N-major)
    const float* __restrict__ b2,
    const float* __restrict__ zf,
    float* __restrict__ outf,                 // zf, or d_out on last step
    unsigned short* __restrict__ zbf,
    float h) {
  __shared__ __align__(16) unsigned short lds[24576];  // 48 KB
  unsigned short* GA = lds;            // 4 bufs x 2048 (32 rows)
  unsigned short* GB = lds + 8192;     // 4 bufs x 4096 (2 chunks of 32 rows)
  const int tid = threadIdx.x;
  const int lane = tid & 63, w = tid >> 6;
  const int l15 = lane & 15, q = lane >> 4, x = l15 & 7;
  const int bid = blockIdx.x;
  const int xcd = bid & 7, loc = bid >> 3;
  const int mt = (loc & 7) | ((xcd & 3) << 3);    // 0..31
  const int nt = (loc >> 3) | ((xcd >> 2) << 3);  // 0..15
  const int m0 = mt * 32, n0 = nt * 64;
  const int brow = (w & 1) * 16 + l15;  // row within B chunk (w>>1)

  f32x4 acc2[2] = {};

  // stage tile t into buf b  (L = 3 loads/thread)
  auto stage_tile = [&](int t, int b) {
    int k = t * 64;
    stage32(Hb, 2048, m0, k, GA + b * 2048, tid);
    stage32(W2T, 2048, n0, k, GB + b * 4096, tid);
    stage32(W2T, 2048, n0 + 32, k, GB + b * 4096 + 2048, tid);
  };
  auto compute = [&](int b) {
    const unsigned short* A = GA + b * 2048;
    const unsigned short* B = GB + b * 4096 + (w >> 1) * 2048;
#pragma unroll
    for (int kk = 0; kk < 2; ++kk) {
      bf16x8 a0 = frag_ld(A, l15, (kk << 2) + q, x);
      bf16x8 a1 = frag_ld(A, 16 + l15, (kk << 2) + q, x);
      bf16x8 bb = frag_ld(B, brow, (kk << 2) + q, x);
      acc2[0] = __builtin_amdgcn_mfma_f32_16x16x32_bf16(a0, bb, acc2[0], 0, 0, 0);
      acc2[1] = __builtin_amdgcn_mfma_f32_16x16x32_bf16(a1, bb, acc2[1], 0, 0, 0);
    }
  };

  stage_tile(0, 0);
  stage_tile(1, 1);
  stage_tile(2, 2);
  for (int i = 0; i < 30; ++i) {
    WAITV(6);    // tile i arrived; tiles i+1, i+2 (6 loads) in flight
    BARRIER();
    if (i < 29) stage_tile(i + 3, (i + 3) & 3);
    compute(i & 3);
  }
  WAITV(3);
  BARRIER();
  compute(30 & 3);
  WAITV(0);
  BARRIER();
  compute(31 & 3);

  // epilogue: wave w covers cols [n0+16w, +16), rows [m0, m0+32)
  {
    int col = n0 + w * 16 + l15;
    float bb = b2[col];
#pragma unroll
    for (int im = 0; im < 2; ++im) {
      int rowb = m0 + im * 16 + q * 4;
#pragma unroll
      for (int r = 0; r < 4; ++r) {
        size_t gidx = (size_t)(rowb + r) * 1024 + col;
        float zv = zf[gidx] + h * (acc2[im][r] + bb);
        outf[gidx] = zv;
        zbf[gidx] = f2bf(zv);
      }
    }
  }
}

// ---------------------------------------------------------------------------
extern "C" void kernel_launch(void* const* d_in, const int* in_sizes, int n_in,
                              void* d_out, int out_size, void* d_ws,
                              size_t ws_size, hipStream_t stream) {
  const float* z0 = (const float*)d_in[0];
  // d_in[1] = t (linspace 0..1, 5) — reproduced exactly in f32 arithmetic
  const float* W1 = (const float*)d_in[2];
  const float* b1 = (const float*)d_in[3];
  const float* W2 = (const float*)d_in[4];
  const float* b2 = (const float*)d_in[5];
  float* out = (float*)d_out;

  char* ws = (char*)d_ws;
  unsigned short* W1T = (unsigned short*)(ws + 0);              // 4 MB
  unsigned short* W2T = (unsigned short*)(ws + (4u << 20));     // 4 MB
  unsigned short* zbf = (unsigned short*)(ws + (8u << 20));     // 2 MB
  unsigned short* Hbf = (unsigned short*)(ws + (10u << 20));    // 4 MB
  float* zf = (float*)(ws + (14u << 20));                       // 4 MB
  float* w1l = (float*)(ws + (18u << 20));                      // 8 KB

  transpose_to_bf16<<<dim3(64, 32), dim3(32, 8), 0, stream>>>(W1, W1T, 1024, 2048);
  transpose_to_bf16<<<dim3(32, 64), dim3(32, 8), 0, stream>>>(W2, W2T, 2048, 1024);
  prep_misc<<<4096, 256, 0, stream>>>(z0, zf, zbf, W1, w1l, 1024 * 1024, 2048);

  const float h = 0.05f;  // (t[i+1]-t[i])/5 in f32 == 0.05f for all segments
  for (int seg = 0; seg < 4; ++seg) {
    float tcur = 0.25f * (float)seg;  // t[seg] (exact in f32)
    for (int j = 0; j < 5; ++j) {
      gemm1_kernel<<<512, 256, 0, stream>>>(zbf, W1T, Hbf, b1, w1l, tcur);
      bool last = (seg == 3 && j == 4);
      float* outf = last ? out : zf;
      gemm2_kernel<<<512, 256, 0, stream>>>(Hbf, W2T, b2, zf, outf, zbf, h);
      tcur += h;  // matches reference's sequential f32 accumulation
    }
  }
}

// Round 9
// 458.793 us; speedup vs baseline: 3.4522x; 1.0578x over previous
//
#include <hip/hip_runtime.h>
#include <cstdint>
#include <cstddef>

// ---------------------------------------------------------------------------
// NeuralODE, multi-kernel + vmcnt-pipelined K-loops, round 9.
//   z' = f(z,t) = tanh([z,t]@W1 + b1) @ W2 + b2, Euler, 20 steps.
//   bs=1024, d=1024, hidden=2048. fp32 in/out; bf16 MFMA inside.
//
// R8 bug: depth-2 prefetch with only 2 LDS buffers -> stage(i+2) raced
// compute(i) on the same buffer (absmax 0.125). Fix: stage AFTER compute,
// behind a second raw s_barrier:
//   WAITV(L); barrier; compute(i&1); barrier; stage(i+2, i&1)
// Buffer is provably free at stage time; prefetch depth stays 2; vmcnt
// never drains in steady state. Tile geometry unchanged from R8:
//   gemm1: 64x128 block, 512 thr (2m x 4n waves of 32x32), grid 256
//   gemm2: 64x64 block K-split-2, 512 thr (2k x 2m x 2n) + LDS f32 reduce
// 2D XCD patch swizzle keeps per-XCD working set ~2.5-3 MB inside its L2.
// ---------------------------------------------------------------------------

typedef __bf16 bf16x8 __attribute__((ext_vector_type(8)));
typedef float f32x4 __attribute__((ext_vector_type(4)));

#define WAITV(N) asm volatile("s_waitcnt vmcnt(" #N ") lgkmcnt(0)" ::: "memory")
#define BARRIER() asm volatile("s_barrier" ::: "memory")

__device__ __forceinline__ unsigned short f2bf(float f) {
  union { float f; unsigned u; } v; v.f = f;
  unsigned r = v.u + 0x7fffu + ((v.u >> 16) & 1u);   // RNE
  return (unsigned short)(r >> 16);
}

// fast tanh: 1 - 2/(1+2^(2*log2e*x)); exact at +/-inf
__device__ __forceinline__ float fast_tanh(float x) {
  float e = __builtin_amdgcn_exp2f(x * 2.8853900817779268f);
  return 1.0f - 2.0f * __builtin_amdgcn_rcpf(1.0f + e);
}

// ---------------- prep: tiled transpose fp32 -> bf16 (out[cols][rows]) ------
__global__ void transpose_to_bf16(const float* __restrict__ in,
                                  unsigned short* __restrict__ out,
                                  int rows, int cols) {
  __shared__ float tile[32][33];
  int c0 = blockIdx.x * 32, r0 = blockIdx.y * 32;
  int tx = threadIdx.x, ty = threadIdx.y;
#pragma unroll
  for (int j = 0; j < 32; j += 8)
    tile[ty + j][tx] = in[(size_t)(r0 + ty + j) * cols + (c0 + tx)];
  __syncthreads();
#pragma unroll
  for (int j = 0; j < 32; j += 8)
    out[(size_t)(c0 + ty + j) * rows + (r0 + tx)] = f2bf(tile[tx][ty + j]);
}

// ---------------- prep: z copies + last W1 row ------------------------------
__global__ void prep_misc(const float* __restrict__ z0,
                          float* __restrict__ zf,
                          unsigned short* __restrict__ zbf,
                          const float* __restrict__ W1,
                          float* __restrict__ w1l, int n, int nl) {
  int i = blockIdx.x * blockDim.x + threadIdx.x;
  if (i < n) { float v = z0[i]; zf[i] = v; zbf[i] = f2bf(v); }
  if (i < nl) { w1l[i] = W1[(size_t)1024 * 2048 + i]; }
}

// stage 64 rows x 64 bf16 (8 KB) with 512 threads via global_load_lds,
// XOR-swizzled 16B chunks: row r slot s holds logical chunk s^(r&7).
__device__ __forceinline__ void stage64(const unsigned short* __restrict__ g,
                                        size_t ld, int row0, int k0,
                                        unsigned short* lds, int tid) {
  int r = tid >> 3;
  int c = (tid & 7) ^ (r & 7);
  __builtin_amdgcn_global_load_lds(
      (const __attribute__((address_space(1))) void*)(
          g + (size_t)(row0 + r) * ld + k0 + c * 8),
      (__attribute__((address_space(3))) void*)(lds + tid * 8), 16, 0, 0);
}

__device__ __forceinline__ bf16x8 frag_ld(const unsigned short* lds, int row,
                                          int chunk_logical, int x) {
  return *(const bf16x8*)(lds + row * 64 + ((chunk_logical ^ x) << 3));
}

// ---------------- GEMM1: H = tanh(Zb @ W1T^T + b1 + t*w1l) ------------------
// 64x128 block, K=1024 (16 BK=64 tiles), 512 thr = 8 waves (2m x 4n, 32x32),
// 2 LDS bufs x 12288 shorts (A 4096 + B 8192). grid 256 (1/CU).
__global__ __launch_bounds__(512, 1) void gemm1_kernel(
    const unsigned short* __restrict__ Zb,    // [1024][1024] bf16
    const unsigned short* __restrict__ W1T,   // [2048][1024] bf16 (N-major)
    unsigned short* __restrict__ H,           // [1024][2048] bf16
    const float* __restrict__ b1, const float* __restrict__ w1l, float tval) {
  __shared__ __align__(16) unsigned short lds[24576];  // 48 KB
  const int tid = threadIdx.x;
  const int lane = tid & 63, wid = tid >> 6;
  const int l15 = lane & 15, q = lane >> 4, x = l15 & 7;
  const int bid = blockIdx.x;
  const int xcd = bid & 7, loc = bid >> 3;
  const int mt = (loc & 3) | ((xcd & 3) << 2);    // 16 m-tiles, 4/XCD
  const int nt = (loc >> 2) | ((xcd >> 2) << 3);  // 16 n-tiles, 8/XCD
  const int m0 = mt * 64, n0 = nt * 128;

  f32x4 acc[2][2] = {};

  auto stage_tile = [&](int t, int b) {   // 3 loads/thread
    int k = t * 64;
    unsigned short* p = lds + b * 12288;
    stage64(Zb, 1024, m0, k, p, tid);
    stage64(W1T, 1024, n0, k, p + 4096, tid);
    stage64(W1T, 1024, n0 + 64, k, p + 8192, tid);
  };
  auto compute = [&](int b) {
    const unsigned short* A = lds + b * 12288 + (wid & 1) * 2048;
    const unsigned short* B = lds + b * 12288 + 4096 + (wid >> 1) * 2048;
#pragma unroll
    for (int kk = 0; kk < 2; ++kk) {
      bf16x8 a[2], bb[2];
#pragma unroll
      for (int im = 0; im < 2; ++im)
        a[im] = frag_ld(A, im * 16 + l15, (kk << 2) + q, x);
#pragma unroll
      for (int jn = 0; jn < 2; ++jn)
        bb[jn] = frag_ld(B, jn * 16 + l15, (kk << 2) + q, x);
#pragma unroll
      for (int im = 0; im < 2; ++im)
#pragma unroll
        for (int jn = 0; jn < 2; ++jn)
          acc[im][jn] = __builtin_amdgcn_mfma_f32_16x16x32_bf16(
              a[im], bb[jn], acc[im][jn], 0, 0, 0);
    }
  };

  stage_tile(0, 0);
  stage_tile(1, 1);
  // iter i: tile i done (tile i+1 in flight, 3 loads); compute; then stage
  // tile i+2 into the buffer compute just freed (behind a barrier).
  for (int i = 0; i < 15; ++i) {
    WAITV(3);
    BARRIER();
    compute(i & 1);
    if (i < 14) {
      BARRIER();                 // all waves done reading buf i&1
      stage_tile(i + 2, i & 1);  // now provably free
    }
  }
  WAITV(0);
  BARRIER();
  compute(1);   // tile 15

#pragma unroll
  for (int jn = 0; jn < 2; ++jn) {
    int col = n0 + (wid >> 1) * 32 + jn * 16 + l15;
    float bb = b1[col] + tval * w1l[col];
#pragma unroll
    for (int im = 0; im < 2; ++im) {
      int rowb = m0 + (wid & 1) * 32 + im * 16 + q * 4;
#pragma unroll
      for (int r = 0; r < 4; ++r)
        H[(size_t)(rowb + r) * 2048 + col] =
            f2bf(fast_tanh(acc[im][jn][r] + bb));
    }
  }
}

// ---------------- GEMM2: z' = zf + h*(H @ W2T^T + b2) -----------------------
// 64x64 block, K=2048 as 16 super-tiles (64 in each K-half), 512 thr = 8
// waves (kh = wid>>2, mh = (wid>>1)&1, nh = wid&1; each 32x32), 2 LDS bufs x
// 16384 shorts (A0,A1,B0,B1 of 4096). LDS f32 reduce of kh=1 into kh=0.
__global__ __launch_bounds__(512, 1) void gemm2_kernel(
    const unsigned short* __restrict__ Hb,    // [1024][2048] bf16
    const unsigned short* __restrict__ W2T,   // [1024][2048] bf16 (N-major)
    const float* __restrict__ b2,
    const float* __restrict__ zf,
    float* __restrict__ outf,                 // zf, or d_out on last step
    unsigned short* __restrict__ zbf,
    float h) {
  __shared__ __align__(16) unsigned short lds[32768];  // 64 KB
  const int tid = threadIdx.x;
  const int lane = tid & 63, wid = tid >> 6;
  const int l15 = lane & 15, q = lane >> 4, x = l15 & 7;
  const int kh = wid >> 2, mh = (wid >> 1) & 1, nh = wid & 1;
  const int bid = blockIdx.x;
  const int xcd = bid & 7, loc = bid >> 3;
  const int mt = (loc & 3) | ((xcd & 3) << 2);    // 16 m-tiles, 4/XCD
  const int nt = (loc >> 2) | ((xcd >> 2) << 3);  // 16 n-tiles, 8/XCD
  const int m0 = mt * 64, n0 = nt * 64;

  f32x4 acc[2][2] = {};

  auto stage_tile = [&](int t, int b) {   // 4 loads/thread
    int k = t * 64;
    unsigned short* p = lds + b * 16384;
    stage64(Hb, 2048, m0, k, p, tid);                   // A kh=0
    stage64(Hb, 2048, m0, k + 1024, p + 4096, tid);     // A kh=1
    stage64(W2T, 2048, n0, k, p + 8192, tid);           // B kh=0
    stage64(W2T, 2048, n0, k + 1024, p + 12288, tid);   // B kh=1
  };
  auto compute = [&](int b) {
    const unsigned short* A = lds + b * 16384 + kh * 4096 + mh * 2048;
    const unsigned short* B = lds + b * 16384 + 8192 + kh * 4096 + nh * 2048;
#pragma unroll
    for (int kk = 0; kk < 2; ++kk) {
      bf16x8 a[2], bb[2];
#pragma unroll
      for (int im = 0; im < 2; ++im)
        a[im] = frag_ld(A, im * 16 + l15, (kk << 2) + q, x);
#pragma unroll
      for (int jn = 0; jn < 2; ++jn)
        bb[jn] = frag_ld(B, jn * 16 + l15, (kk << 2) + q, x);
#pragma unroll
      for (int im = 0; im < 2; ++im)
#pragma unroll
        for (int jn = 0; jn < 2; ++jn)
          acc[im][jn] = __builtin_amdgcn_mfma_f32_16x16x32_bf16(
              a[im], bb[jn], acc[im][jn], 0, 0, 0);
    }
  };

  stage_tile(0, 0);
  stage_tile(1, 1);
  for (int i = 0; i < 15; ++i) {
    WAITV(4);
    BARRIER();
    compute(i & 1);
    if (i < 14) {
      BARRIER();                 // all waves done reading buf i&1
      stage_tile(i + 2, i & 1);  // now provably free
    }
  }
  WAITV(0);
  BARRIER();
  compute(1);   // tile 15

  // K-split reduce: kh=1 waves publish to LDS (f32, stride 33), kh=0 add.
  __syncthreads();
  float* red = (float*)lds;
  const int region = (mh * 2 + nh) * 1056;   // 32*33 floats per (mh,nh)
  if (kh == 1) {
#pragma unroll
    for (int im = 0; im < 2; ++im)
#pragma unroll
      for (int jn = 0; jn < 2; ++jn) {
        int c = jn * 16 + l15;
#pragma unroll
        for (int r = 0; r < 4; ++r)
          red[region + (im * 16 + q * 4 + r) * 33 + c] = acc[im][jn][r];
      }
  }
  __syncthreads();
  if (kh == 0) {
#pragma unroll
    for (int jn = 0; jn < 2; ++jn) {
      int coll = nh * 32 + jn * 16 + l15;
      int col = n0 + coll;
      float bb = b2[col];
#pragma unroll
      for (int im = 0; im < 2; ++im) {
        int rowl = im * 16 + q * 4;
#pragma unroll
        for (int r = 0; r < 4; ++r) {
          float s = acc[im][jn][r] +
                    red[region + (rowl + r) * 33 + jn * 16 + l15];
          size_t gidx = (size_t)(m0 + mh * 32 + rowl + r) * 1024 + col;
          float zv = zf[gidx] + h * (s + bb);
          outf[gidx] = zv;
          zbf[gidx] = f2bf(zv);
        }
      }
    }
  }
}

// ---------------------------------------------------------------------------
extern "C" void kernel_launch(void* const* d_in, const int* in_sizes, int n_in,
                              void* d_out, int out_size, void* d_ws,
                              size_t ws_size, hipStream_t stream) {
  const float* z0 = (const float*)d_in[0];
  // d_in[1] = t (linspace 0..1, 5) — reproduced exactly in f32 arithmetic
  const float* W1 = (const float*)d_in[2];
  const float* b1 = (const float*)d_in[3];
  const float* W2 = (const float*)d_in[4];
  const float* b2 = (const float*)d_in[5];
  float* out = (float*)d_out;

  char* ws = (char*)d_ws;
  unsigned short* W1T = (unsigned short*)(ws + 0);              // 4 MB
  unsigned short* W2T = (unsigned short*)(ws + (4u << 20));     // 4 MB
  unsigned short* zbf = (unsigned short*)(ws + (8u << 20));     // 2 MB
  unsigned short* Hbf = (unsigned short*)(ws + (10u << 20));    // 4 MB
  float* zf = (float*)(ws + (14u << 20));                       // 4 MB
  float* w1l = (float*)(ws + (18u << 20));                      // 8 KB

  transpose_to_bf16<<<dim3(64, 32), dim3(32, 8), 0, stream>>>(W1, W1T, 1024, 2048);
  transpose_to_bf16<<<dim3(32, 64), dim3(32, 8), 0, stream>>>(W2, W2T, 2048, 1024);
  prep_misc<<<4096, 256, 0, stream>>>(z0, zf, zbf, W1, w1l, 1024 * 1024, 2048);

  const float h = 0.05f;  // (t[i+1]-t[i])/5 in f32 == 0.05f for all segments
  for (int seg = 0; seg < 4; ++seg) {
    float tcur = 0.25f * (float)seg;  // t[seg] (exact in f32)
    for (int j = 0; j < 5; ++j) {
      gemm1_kernel<<<256, 512, 0, stream>>>(zbf, W1T, Hbf, b1, w1l, tcur);
      bool last = (seg == 3 && j == 4);
      float* outf = last ? out : zf;
      gemm2_kernel<<<256, 512, 0, stream>>>(Hbf, W2T, b2, zf, outf, zbf, h);
      tcur += h;  // matches reference's sequential f32 accumulation
    }
  }
}